// Round 9
// baseline (290.526 us; speedup 1.0000x reference)
//
#include <hip/hip_runtime.h>
#include <hip/hip_bf16.h>
#include <math.h>

#define B_ 1024
#define S_ 200
#define D_ 128
#define H_ 128
#define N_ 64

typedef __attribute__((ext_vector_type(8))) short short8;
typedef __attribute__((ext_vector_type(8))) __bf16 bf16x8;
typedef __attribute__((ext_vector_type(4))) float floatx4;

typedef __attribute__((address_space(1))) void gvoid_t;
typedef __attribute__((address_space(3))) void lvoid_t;

static __device__ __forceinline__ float bf2f(unsigned short u) {
    union { unsigned int i; float f; } v; v.i = ((unsigned int)u) << 16; return v.f;
}
static __device__ __forceinline__ unsigned short f2bf(float f) {
    union { float f; unsigned int u; } v; v.f = f;
    unsigned int u = v.u;
    return (unsigned short)((u + 0x7FFFu + ((u >> 16) & 1u)) >> 16);   // RNE
}
static __device__ __forceinline__ float ld1(const void* p, int isbf, size_t i) {
    return isbf ? bf2f(((const unsigned short*)p)[i]) : ((const float*)p)[i];
}
static __device__ __forceinline__ float fast_tanh(float x) {
    float t = __expf(2.0f * x);
    return 1.0f - 2.0f * __builtin_amdgcn_rcpf(t + 1.0f);   // err ~2e-5
}
static __device__ __forceinline__ void gload_lds16(const void* g, void* l) {
    __builtin_amdgcn_global_load_lds((const gvoid_t*)g, (lvoid_t*)l, 16, 0, 0);
}

// pure-LDS barrier: own-wave lgkm drain + barrier (no vmcnt drain -> staging stays in flight)
#define LBAR() { asm volatile("s_waitcnt lgkmcnt(0)" ::: "memory"); __builtin_amdgcn_s_barrier(); }

// ---- wave-local dtype detection (no barriers; every wave computes the same flag) ----
static __device__ __forceinline__ int detect_wave_256(const void* p) {
    int lane = threadIdx.x & 63;
    uint4 w = ((const uint4*)p)[lane];
    unsigned int ws[4] = {w.x, w.y, w.z, w.w};
    int pass = 0;
#pragma unroll
    for (int k = 0; k < 4; ++k) {
        unsigned int e = (ws[k] >> 7) & 0xFF;
        pass += (e == 0 || (e >= 96 && e <= 140)) ? 1 : 0;
    }
#pragma unroll
    for (int off = 32; off; off >>= 1) pass += __shfl_xor(pass, off, 64);
    return pass * 4 >= 256 * 3;
}
static __device__ __forceinline__ int detect_wave_64(const void* p) {
    int lane = threadIdx.x & 63;
    unsigned int w = ((const unsigned int*)p)[lane];
    unsigned int e = (w >> 7) & 0xFF;
    int pass = (e == 0 || (e >= 96 && e <= 140)) ? 1 : 0;
#pragma unroll
    for (int off = 32; off; off >>= 1) pass += __shfl_xor(pass, off, 64);
    return pass * 4 >= 64 * 3;
}
static __device__ __forceinline__ int detect_mask_u8(const void* p) {
    int lane = threadIdx.x & 63;
    uint4 w = ((const uint4*)p)[lane];
    unsigned int x = (w.x | w.y | w.z | w.w) & 0xFFFFFF00u;
    return (__ballot(x != 0) != 0ULL) ? 1 : 0;
}

// ---------------- prep: block 0 -> WeTf + pbLh tail + gsum/cnt; blocks 1..200 -> pbLh ----
// WeTf layout: frag = nt*4+kks; WeTf[(frag*64+lane)*8+j] = We[kks*32+(lane>>4)*8+j][nt*16+(lane&15)]
// pbLh (bf16, per-lane C-frag order): ushort idx ((mt*8+nt)*64 + quad*16 + mrow)*4 + reg
//   = pb[s = mt*16+quad*4+reg][h = nt*16+mrow]. mt=12 s>=200 entries zero-filled.
__global__ __launch_bounds__(128) void prep_kernel(
    const void* __restrict__ We, const void* __restrict__ pos,
    const void* __restrict__ Wp,
    unsigned short* __restrict__ WeTf, unsigned short* __restrict__ pbLh,
    float* __restrict__ gsum, unsigned int* __restrict__ cnt)
{
    int blk = blockIdx.x, t = threadIdx.x;
    __shared__ unsigned short T[128][136];
    __shared__ float prow[D_];
    __shared__ int fl[2];
    if (blk == 0) {
        if (t == 0) { *gsum = 0.f; *cnt = 0u; }
        if (t < 64) { int f = detect_wave_256(We); if (t == 0) fl[0] = f; }
        __syncthreads();
        int fWe = fl[0];
        for (int c = t; c < 2048; c += 128) {
            int d = c >> 4, h8 = (c & 15) * 8;
            short8 v;
            if (fWe) {
                v = *(const short8*)((const unsigned short*)We + d * H_ + h8);
            } else {
                const float* p = (const float*)We + d * H_ + h8;
                float4 a = ((const float4*)p)[0], b = ((const float4*)p)[1];
                v[0] = (short)f2bf(a.x); v[1] = (short)f2bf(a.y);
                v[2] = (short)f2bf(a.z); v[3] = (short)f2bf(a.w);
                v[4] = (short)f2bf(b.x); v[5] = (short)f2bf(b.y);
                v[6] = (short)f2bf(b.z); v[7] = (short)f2bf(b.w);
            }
            *(short8*)(&T[d][h8]) = v;
        }
        __syncthreads();
        for (int i = t; i < 2048; i += 128) {
            int frag = i >> 6, ln = i & 63;
            int nt = frag >> 2, kks = frag & 3;
            int h = nt * 16 + (ln & 15);
            int dbase = kks * 32 + (ln >> 4) * 8;
            short8 v;
#pragma unroll
            for (int j = 0; j < 8; ++j) v[j] = (short)T[dbase + j][h];
            *(short8*)(WeTf + (size_t)i * 8) = v;
        }
        // zero-fill pbLh entries for mt=12, s_local >= 8 (s = 200..207)
        for (int i = t; i < 1024; i += 128) {
            int nt = i >> 7, j = i & 127;
            int q = 2 + (j >> 6), m = (j >> 2) & 15, r = j & 3;
            pbLh[(((96 + nt) * 64 + q * 16 + m) << 2) + r] = 0;
        }
    } else {
        if (t < 64)       { int f = detect_wave_256(pos); if (t == 0)  fl[0] = f; }
        else if (t < 128) { int f = detect_wave_256(Wp);  if (t == 64) fl[1] = f; }
        __syncthreads();
        int fPos = fl[0], fWp = fl[1];
        int s = blk - 1, h = t;
        prow[h] = ld1(pos, fPos, (size_t)s * D_ + h);
        __syncthreads();
        float acc = 0.f;
        if (fWp) {
            const unsigned short* W = (const unsigned short*)Wp;
            for (int d = 0; d < D_; ++d) acc = fmaf(prow[d], bf2f(W[d * H_ + h]), acc);
        } else {
            const float* W = (const float*)Wp;
            for (int d = 0; d < D_; ++d) acc = fmaf(prow[d], W[d * H_ + h], acc);
        }
        int mt = s >> 4, qr = s & 15;
        int idx = (((mt * 8 + (h >> 4)) * 64 + (qr >> 2) * 16 + (h & 15)) << 2) + (qr & 3);
        pbLh[idx] = f2bf(acc);
    }
}

// ---------------- fused: 256 blocks (1/CU), 4 b's per block, double-buffered Xsh -------
// Per iteration: load b's small inputs -> fire-and-forget stage of b+1 into other buffer
// -> compute b (pure-LDS barriers) -> vmcnt(0)+barrier at swap. Next-b HBM stream hides
// under current-b compute. Tables (WeTf/pbLh) read once per block (x4 fewer than before).
__global__ __launch_bounds__(512, 2) void fused_kernel(
    const void* __restrict__ Xs, const void* __restrict__ Xitem,
    const void* __restrict__ maskv, const void* __restrict__ origin,
    const unsigned short* __restrict__ WeTf, const unsigned short* __restrict__ pbLh,
    const void* __restrict__ zv,
    float* __restrict__ neg_sum, float* __restrict__ gsum,
    unsigned int* __restrict__ cnt, float* __restrict__ out)
{
    int t = threadIdx.x;
    int wv = t >> 6, lane = t & 63;
    int quad = lane >> 4, mrow = lane & 15;

    __shared__ __align__(16) unsigned short Xsh[2][S_ * D_];   // 102400 B
    __shared__ __align__(16) float ubuf[4096];                 // sp[8][208] | partial[32][128]
    __shared__ float red4[512];
    __shared__ float attn[200];
    __shared__ float outv[D_];
    __shared__ float red[40];
    __shared__ int lastflag;

    float* sp = ubuf;   // [8][208]

    // --- once per block: detects (consumed immediately) ---
    int fXs = detect_wave_256(Xs);
    int fXi = detect_wave_256(Xitem);
    int fOr = detect_wave_256(origin);
    int fz  = detect_wave_64(zv);
    int fMk = detect_mask_u8(maskv);

    // --- once per block: B fragments, z, pb (all register-resident) ---
    int nt = wv;
    bf16x8 bfr[4];
#pragma unroll
    for (int kks = 0; kks < 4; ++kks)
        bfr[kks] = __builtin_bit_cast(bf16x8,
            *(const short8*)(WeTf + (size_t)((((nt << 2) + kks) << 6) + lane) * 8));
    float zl = ld1(zv, fz, nt * 16 + mrow);
    uint2 pbh[13];
#pragma unroll
    for (int m2 = 0; m2 < 13; ++m2)
        pbh[m2] = *(const uint2*)(pbLh + (size_t)(((m2 * 8 + nt) * 64 + lane) << 2));

    auto stage = [&](int buf, int bb) {
        unsigned short* dst = &Xsh[buf][0];
        if (fXs) {
            const unsigned short* g16 = (const unsigned short*)Xs + (size_t)bb * S_ * D_;
            for (int i = t; i < S_ * 16; i += 512) {
                int s = i >> 4, c8 = (i & 15) * 8;
                gload_lds16(g16 + (size_t)s * D_ + (c8 ^ ((s & 7) << 3)), dst + (size_t)i * 8);
            }
        } else {
            const float* g32 = (const float*)Xs + (size_t)bb * S_ * D_;
            for (int i = t; i < S_ * 16; i += 512) {
                int s = i >> 4, c8 = (i & 15) * 8;
                const float* p = g32 + (size_t)s * D_ + c8;
                float4 a = ((const float4*)p)[0], c = ((const float4*)p)[1];
                short8 v;
                v[0] = (short)f2bf(a.x); v[1] = (short)f2bf(a.y);
                v[2] = (short)f2bf(a.z); v[3] = (short)f2bf(a.w);
                v[4] = (short)f2bf(c.x); v[5] = (short)f2bf(c.y);
                v[6] = (short)f2bf(c.z); v[7] = (short)f2bf(c.w);
                *(short8*)(dst + s * D_ + (c8 ^ ((s & 7) << 3))) = v;
            }
        }
    };

    int b0 = blockIdx.x * 4;

    // --- prologue: stage b0 into buffer 0, full drain ---
    stage(0, b0);
    asm volatile("s_waitcnt vmcnt(0)" ::: "memory");
    LBAR();

#pragma unroll 1
    for (int ib = 0; ib < 4; ++ib) {
        int b = b0 + ib;
        int buf = ib & 1;
        const unsigned short* Xb = &Xsh[buf][0];
        const float* Xg32 = (const float*)Xs + (size_t)b * S_ * D_;

        // --- (1) per-b small loads (issued before next-b stage queue) ---
        int len = 0;
#pragma unroll
        for (int k = 0; k < 4; ++k) {
            int s = lane + 64 * k;
            int nzv = 0;
            if (s < S_)
                nzv = fMk ? (((const unsigned char*)maskv)[(size_t)b * S_ + s] != 0)
                          : (((const int*)maskv)[(size_t)b * S_ + s] != 0);
            len += __popcll(__ballot(nzv));
        }
        int last = len - 1;
        float xiv = (t < D_) ? ld1(Xitem, fXi, (size_t)b * D_ + t) : 0.f;
        int nn = t >> 3, part = t & 7;
        float o_f[16];
        if (fOr) {
            const unsigned short* p = (const unsigned short*)origin + ((size_t)b * N_ + nn) * D_ + part * 16;
#pragma unroll
            for (int j = 0; j < 2; ++j) {
                uint4 u = *(const uint4*)(p + j * 8);
                o_f[j*8+0] = bf2f((unsigned short)(u.x & 0xffff));
                o_f[j*8+1] = bf2f((unsigned short)(u.x >> 16));
                o_f[j*8+2] = bf2f((unsigned short)(u.y & 0xffff));
                o_f[j*8+3] = bf2f((unsigned short)(u.y >> 16));
                o_f[j*8+4] = bf2f((unsigned short)(u.z & 0xffff));
                o_f[j*8+5] = bf2f((unsigned short)(u.z >> 16));
                o_f[j*8+6] = bf2f((unsigned short)(u.w & 0xffff));
                o_f[j*8+7] = bf2f((unsigned short)(u.w >> 16));
            }
        } else {
            const float* p = (const float*)origin + ((size_t)b * N_ + nn) * D_ + part * 16;
#pragma unroll
            for (int j = 0; j < 4; ++j) {
                float4 v = *(const float4*)(p + j * 4);
                o_f[j*4+0] = v.x; o_f[j*4+1] = v.y; o_f[j*4+2] = v.z; o_f[j*4+3] = v.w;
            }
        }

        // --- (2) fire-and-forget: stage next b into the other buffer ---
        if (ib < 3) stage(buf ^ 1, b + 1);

        // --- (3) phase A: 13 m-tiles from Xsh[buf]; sp[nt][s] per-wave partials ---
#pragma unroll
        for (int mt = 0; mt < 13; ++mt) {
            int r_ = mt * 16 + mrow; if (r_ > 199) r_ = 199;   // tail rows discarded below
            int rbase_ = r_ * D_, rx_ = (r_ & 7) << 3;
            floatx4 acc_;
            acc_[0] = bf2f((unsigned short)(pbh[mt].x & 0xffff));
            acc_[1] = bf2f((unsigned short)(pbh[mt].x >> 16));
            acc_[2] = bf2f((unsigned short)(pbh[mt].y & 0xffff));
            acc_[3] = bf2f((unsigned short)(pbh[mt].y >> 16));
#pragma unroll
            for (int kk = 0; kk < 4; ++kk) {
                bf16x8 af = __builtin_bit_cast(bf16x8,
                    *(const short8*)(Xb + rbase_ + ((kk * 32 + quad * 8) ^ rx_)));
                acc_ = __builtin_amdgcn_mfma_f32_16x16x32_bf16(af, bfr[kk], acc_, 0, 0, 0);
            }
#pragma unroll
            for (int rr = 0; rr < 4; ++rr) {
                float v_ = fast_tanh(acc_[rr]) * zl;
                v_ += __shfl_xor(v_, 1, 64);
                v_ += __shfl_xor(v_, 2, 64);
                v_ += __shfl_xor(v_, 4, 64);
                v_ += __shfl_xor(v_, 8, 64);
                int s_ = mt * 16 + quad * 4 + rr;
                if (mrow == 0 && s_ < S_) sp[nt * 208 + s_] = v_;
            }
        }
        LBAR();                                                // S1: sp ready

        // --- (4) softmax by wave 0 ---
        if (wv == 0) {
            int sb = lane * 4;
            float s0 = 0.f, s1 = 0.f, s2 = 0.f, s3 = 0.f;
            if (lane < 50) {
#pragma unroll
                for (int n8 = 0; n8 < 8; ++n8) {
                    float4 q = *(const float4*)(sp + n8 * 208 + sb);
                    s0 += q.x; s1 += q.y; s2 += q.z; s3 += q.w;
                }
            }
            float m0 = (sb + 0 < len) ? s0 : -INFINITY;
            float m1 = (sb + 1 < len) ? s1 : -INFINITY;
            float m2 = (sb + 2 < len) ? s2 : -INFINITY;
            float m3 = (sb + 3 < len) ? s3 : -INFINITY;
            float m = fmaxf(fmaxf(m0, m1), fmaxf(m2, m3));
#pragma unroll
            for (int off = 32; off; off >>= 1) m = fmaxf(m, __shfl_xor(m, off, 64));
            float e0 = (sb + 0 < len) ? __expf(s0 - m) : 0.f;
            float e1 = (sb + 1 < len) ? __expf(s1 - m) : 0.f;
            float e2 = (sb + 2 < len) ? __expf(s2 - m) : 0.f;
            float e3 = (sb + 3 < len) ? __expf(s3 - m) : 0.f;
            float l = e0 + e1 + e2 + e3;
#pragma unroll
            for (int off = 32; off; off >>= 1) l += __shfl_xor(l, off, 64);
            float inv = 1.0f / l;
            if (lane < 50) {
                float4 av = {e0 * inv, e1 * inv, e2 * inv, e3 * inv};
                *(float4*)(attn + sb) = av;
            }
        }
        LBAR();                                                // S2: attn ready

        // --- (5) weighted sum: partial[32][128] from Xsh[buf] ---
        {
            int spi = t >> 4;          // 0..31
            int d8 = (t & 15) * 8;     // 0..120
            float a0 = 0.f, a1 = 0.f, a2 = 0.f, a3 = 0.f;
            float a4 = 0.f, a5 = 0.f, a6 = 0.f, a7 = 0.f;
            if (fXs) {
                for (int s = spi; s < S_; s += 32) {
                    float ww = attn[s];
                    short8 v2 = *(const short8*)(Xb + s * D_ + (d8 ^ ((s & 7) << 3)));
                    a0 = fmaf(ww, bf2f((unsigned short)v2[0]), a0);
                    a1 = fmaf(ww, bf2f((unsigned short)v2[1]), a1);
                    a2 = fmaf(ww, bf2f((unsigned short)v2[2]), a2);
                    a3 = fmaf(ww, bf2f((unsigned short)v2[3]), a3);
                    a4 = fmaf(ww, bf2f((unsigned short)v2[4]), a4);
                    a5 = fmaf(ww, bf2f((unsigned short)v2[5]), a5);
                    a6 = fmaf(ww, bf2f((unsigned short)v2[6]), a6);
                    a7 = fmaf(ww, bf2f((unsigned short)v2[7]), a7);
                }
            } else {
                for (int s = spi; s < S_; s += 32) {
                    float ww = attn[s];
                    const float* p = Xg32 + (size_t)s * D_ + d8;
                    float4 u0 = ((const float4*)p)[0], u1 = ((const float4*)p)[1];
                    a0 = fmaf(ww, u0.x, a0); a1 = fmaf(ww, u0.y, a1);
                    a2 = fmaf(ww, u0.z, a2); a3 = fmaf(ww, u0.w, a3);
                    a4 = fmaf(ww, u1.x, a4); a5 = fmaf(ww, u1.y, a5);
                    a6 = fmaf(ww, u1.z, a6); a7 = fmaf(ww, u1.w, a7);
                }
            }
            float4 w0 = {a0, a1, a2, a3}, w1 = {a4, a5, a6, a7};
            *(float4*)(ubuf + spi * D_ + d8)     = w0;   // sp is dead now
            *(float4*)(ubuf + spi * D_ + d8 + 4) = w1;
        }
        LBAR();                                                // S3: partial ready
        {
            int g = t >> 7, d = t & 127;
            float sgp = 0.f;
#pragma unroll
            for (int p = 0; p < 8; ++p) sgp += ubuf[(g * 8 + p) * D_ + d];
            red4[g * D_ + d] = sgp;
        }
        LBAR();                                                // S4: red4 ready

        // --- (6) epilogue reductions, out write ---
        if (t < D_) {
            float att = red4[t] + red4[D_ + t] + red4[2 * D_ + t] + red4[3 * D_ + t];
            float xl = fXs ? bf2f(Xb[last * D_ + (t ^ ((last & 7) << 3))])
                           : Xg32[(size_t)last * D_ + t];
            float lv = attn[last] * xl;
            float ov = att - lv;                 // out_vec = attention_output - last_vec
            outv[t] = ov;
            out[(size_t)b * (D_ + 1) + t] = att;
            float r0 = att * xiv;                // inner
            float r1 = lv * lv, r2 = lv * ov, r3 = ov * ov;
#pragma unroll
            for (int off = 32; off; off >>= 1) {
                r0 += __shfl_xor(r0, off, 64);
                r1 += __shfl_xor(r1, off, 64);
                r2 += __shfl_xor(r2, off, 64);
                r3 += __shfl_xor(r3, off, 64);
            }
            if (lane == 0) { red[wv] = r0; red[8 + wv] = r1; red[16 + wv] = r2; red[24 + wv] = r3; }
        }
        LBAR();                                                // S5: red/outv ready
        float vv = red[24] + red[25];            // ||out_vec||^2 (all threads)
        if (t == 0) {
            out[(size_t)b * (D_ + 1) + D_] = red[0] + red[1];
            float ll = red[8] + red[9], lo = red[16] + red[17];
            float cosv = lo / (sqrtf(fmaxf(ll, 1e-12f)) * sqrtf(fmaxf(vv, 1e-12f)));
            float pl = 0.5f * (1.f - cosv);
            atomicAdd(gsum, log1pf(expf(-pl)));  // global pos-loss sum
        }

        // --- (7) neg losses: thread (nn, part) eighth-dot; pure shuffle reduction ---
        {
            float o_oo = 0.f, o_ov = 0.f;
#pragma unroll
            for (int j = 0; j < 16; ++j) {
                float wv_ = outv[part * 16 + j];
                o_oo = fmaf(o_f[j], o_f[j], o_oo);
                o_ov = fmaf(o_f[j], wv_, o_ov);
            }
            o_oo += __shfl_xor(o_oo, 1, 64); o_ov += __shfl_xor(o_ov, 1, 64);
            o_oo += __shfl_xor(o_oo, 2, 64); o_ov += __shfl_xor(o_ov, 2, 64);
            o_oo += __shfl_xor(o_oo, 4, 64); o_ov += __shfl_xor(o_ov, 4, 64);
            float ns = 0.f;
            if (part == 0) {
                float cosn = o_ov / (sqrtf(fmaxf(o_oo, 1e-12f)) * sqrtf(fmaxf(vv, 1e-12f)));
                float nl = 0.5f * (1.f - cosn);
                ns = log1pf(expf(nl));
            }
            ns += __shfl_xor(ns, 8, 64);
            ns += __shfl_xor(ns, 16, 64);
            ns += __shfl_xor(ns, 32, 64);
            if (lane == 0) red[32 + wv] = ns;
        }
        LBAR();                                                // S6
        if (t == 0) {
            float nsum = red[32] + red[33] + red[34] + red[35]
                       + red[36] + red[37] + red[38] + red[39];
            neg_sum[b] = nsum;
            __threadfence();
            unsigned int my = atomicAdd(cnt, 1u);
            lastflag = (my == B_ - 1) ? 1 : 0;
        }
        LBAR();                                                // S7
        if (lastflag) {                                        // globally-last b: aux row
            __threadfence();
            float gs = *(volatile float*)gsum;
            for (int b2 = t; b2 < B_; b2 += 512)
                out[(size_t)B_ * (D_ + 1) + b2] = gs + neg_sum[b2];
        }

        // --- (8) swap: next-b staging must be complete ---
        asm volatile("s_waitcnt vmcnt(0)" ::: "memory");
        __syncthreads();
    }
}

extern "C" void kernel_launch(void* const* d_in, const int* in_sizes, int n_in,
                              void* d_out, int out_size, void* d_ws, size_t ws_size,
                              hipStream_t stream) {
    const void* Xs     = d_in[0]; // X_series [B,S,D]
    const void* pos    = d_in[1]; // pos_series [S,D]
    const void* Xitem  = d_in[2]; // X_item [B,D]
    const void* mask   = d_in[3]; // valid_mask [B,S]
    const void* origin = d_in[4]; // origin [B,N,D]
    const void* Wp     = d_in[5]; // [D,H]
    const void* We     = d_in[6]; // [D,H]
    const void* zv     = d_in[7]; // [H]

    unsigned short* WeTf = (unsigned short*)d_ws;                  // 32 KB swizzled
    unsigned short* pbLh = (unsigned short*)((char*)d_ws + 32768); // 13*8*64*4 bf16 = 52 KB
    float* neg_sum  = (float*)((char*)d_ws + 32768 + 53248);       // 1024 f32
    float* gsum     = neg_sum + B_;                                // 1 f32
    unsigned int* cnt = (unsigned int*)(gsum + 1);                 // 1 u32
    float* out = (float*)d_out;                                    // f32 output

    prep_kernel<<<201, 128, 0, stream>>>(We, pos, Wp, WeTf, pbLh, gsum, cnt);
    fused_kernel<<<B_ / 4, 512, 0, stream>>>(Xs, Xitem, mask, origin, WeTf, pbLh, zv,
                                             neg_sum, gsum, cnt, out);
}